// Round 1
// baseline (812.977 us; speedup 1.0000x reference)
//
#include <hip/hip_runtime.h>
#include <math.h>

#define S_LEN 4096
#define N_FEAT 64
#define N_BATCH 16
#define N_SCALES 8
#define THRESH 1e-4f

struct ScaleParams {
    int L[N_SCALES];
    int Lpad[N_SCALES];
    int off[N_SCALES];
    float inv_sqrt_scale[N_SCALES];
    float step[N_SCALES];
};

// ---------------- prep: build dilated, interpolated, normalized kernels ----
__global__ void build_kernels(const float* __restrict__ mother,
                              float* __restrict__ kern,
                              ScaleParams p, int total) {
    int i = blockIdx.x * blockDim.x + threadIdx.x;
    if (i >= total) return;
    int idx = 0;
#pragma unroll
    for (int s = 1; s < N_SCALES; ++s)
        if (i >= p.off[s]) idx = s;
    int l = i - p.off[idx];
    float v = 0.f;
    if (l < p.L[idx]) {
        float xq = l * p.step[idx];          // linspace(0, 63, L)
        xq = fminf(xq, 63.0f);
        int i0 = (int)xq;
        if (i0 > 62) i0 = 62;
        float frac = xq - (float)i0;
        float a = mother[idx * 64 + i0];
        float b = mother[idx * 64 + i0 + 1];
        v = (a + (b - a) * frac) * p.inv_sqrt_scale[idx];
    }
    kern[i] = v;
}

// ---------------- conv body ------------------------------------------------
template <bool GUARD>
__device__ __forceinline__ void conv_body(const float* __restrict__ sigb,
                                          const float* __restrict__ klds,
                                          float acc[16], int tw0, int Lpad) {
    int lb_end = Lpad;
    if (GUARD) lb_end = min(Lpad, tw0 + 16);   // taps beyond t contribute 0

    for (int lb = 0; lb < lb_end; lb += 16) {
        float k[16];
#pragma unroll
        for (int c = 0; c < 16; c += 4) {
            const float4 kk = *reinterpret_cast<const float4*>(&klds[lb + c]);
            k[c] = kk.x; k[c + 1] = kk.y; k[c + 2] = kk.z; k[c + 3] = kk.w;
        }
        const int base = tw0 - lb - 15;
        float X[31];
#pragma unroll
        for (int m = 0; m < 31; ++m) {
            const int s = base + m;
            if (GUARD) {
                const int sc = (s < 0) ? 0 : s;
                float v = sigb[(size_t)sc * N_FEAT];
                X[m] = (s < 0) ? 0.f : v;
            } else {
                X[m] = sigb[(size_t)s * N_FEAT];
            }
        }
#pragma unroll
        for (int c = 0; c < 16; ++c)
#pragma unroll
            for (int j = 0; j < 16; ++j)
                acc[j] = fmaf(k[c], X[15 + j - c], acc[j]);
    }
}

__global__ __launch_bounds__(256) void wavelet_conv(
    const float* __restrict__ sig,     // [B, S, F]
    const float* __restrict__ kern_g,  // padded dilated kernels (ws)
    const float* __restrict__ sw,      // [8] scale weights
    float* __restrict__ out,           // [B, 8, S, F]
    ScaleParams p) {
    const int idx = blockIdx.y;
    const int b = blockIdx.z;
    const int t0 = blockIdx.x * 64;
    const int wave = threadIdx.x >> 6;
    const int f = threadIdx.x & 63;
    const int Lpad = p.Lpad[idx];

    __shared__ float klds[2048];
    for (int i = threadIdx.x; i < Lpad; i += 256)
        klds[i] = kern_g[p.off[idx] + i];
    __syncthreads();

    const int tw0 = t0 + wave * 16;
    const float* sigb = sig + (size_t)b * S_LEN * N_FEAT + f;

    float acc[16];
#pragma unroll
    for (int j = 0; j < 16; ++j) acc[j] = 0.f;

    if (tw0 >= Lpad)
        conv_body<false>(sigb, klds, acc, tw0, Lpad);
    else
        conv_body<true>(sigb, klds, acc, tw0, Lpad);

    const float w = sw[idx];
    float* ob = out + (((size_t)b * N_SCALES + idx) * S_LEN + tw0) * N_FEAT + f;
#pragma unroll
    for (int j = 0; j < 16; ++j) {
        float v = acc[j] * w;
        ob[(size_t)j * N_FEAT] = (fabsf(v) > THRESH) ? v : 0.f;
    }
}

// ---------------- host -----------------------------------------------------
extern "C" void kernel_launch(void* const* d_in, const int* in_sizes, int n_in,
                              void* d_out, int out_size, void* d_ws, size_t ws_size,
                              hipStream_t stream) {
    const float* sig    = (const float*)d_in[0];
    const float* mother = (const float*)d_in[1];
    const float* sw     = (const float*)d_in[2];
    float* out  = (float*)d_out;
    float* kern = (float*)d_ws;

    ScaleParams p;
    int off = 0;
    const double log10_32 = log10(32.0);
    for (int i = 0; i < N_SCALES; ++i) {
        double scale = pow(10.0, (double)i * log10_32 / 7.0);
        double v = 64.0 * scale;
        double r = floor(v + 0.5);
        int L = (fabs(v - r) < 1e-6) ? (int)r : (int)v;  // snap exact ints (i=0,7)
        p.L[i] = L;
        p.Lpad[i] = (L + 15) & ~15;
        p.off[i] = off;
        off += p.Lpad[i];
        p.inv_sqrt_scale[i] = (float)(1.0 / sqrt(scale));
        p.step[i] = (float)(63.0 / (double)(L - 1));
    }
    const int total = off;  // 5168 floats, needs ~21 KB of ws

    build_kernels<<<dim3((total + 255) / 256), dim3(256), 0, stream>>>(
        mother, kern, p, total);

    dim3 grid(S_LEN / 64, N_SCALES, N_BATCH);
    wavelet_conv<<<grid, dim3(256), 0, stream>>>(sig, kern, sw, out, p);
}

// Round 2
// 271.457 us; speedup vs baseline: 2.9949x; 2.9949x over previous
//
#include <hip/hip_runtime.h>
#include <hip/hip_bf16.h>
#include <math.h>

#define S_LEN 4096
#define N_FEAT 64
#define N_BATCH 16
#define N_SCALES 8
#define THRESH 1e-4f
#define PADL 2048
#define XT_STRIDE (PADL + S_LEN)   // 6144 bf16 elems per (b,f) row

typedef unsigned short ushort_t;
typedef __attribute__((ext_vector_type(8))) short bf16x8;
typedef __attribute__((ext_vector_type(16))) float f32x16;

struct ScaleParams {
    int L[N_SCALES], Lpad[N_SCALES], off[N_SCALES];
    int Mc[N_SCALES], Aoff[N_SCALES];          // Aoff in ushort elems
    float inv_sqrt_scale[N_SCALES], step[N_SCALES];
};

// ---- prep 1: dilated, interpolated, normalized kernels (fp32, Lpad-padded) --
__global__ void build_kernels(const float* __restrict__ mother,
                              float* __restrict__ kern,
                              ScaleParams p, int total) {
    int i = blockIdx.x * blockDim.x + threadIdx.x;
    if (i >= total) return;
    int idx = 0;
#pragma unroll
    for (int s = 1; s < N_SCALES; ++s)
        if (i >= p.off[s]) idx = s;
    int l = i - p.off[idx];
    float v = 0.f;
    if (l < p.L[idx]) {
        float xq = fminf(l * p.step[idx], 63.0f);
        int i0 = (int)xq; if (i0 > 62) i0 = 62;
        float frac = xq - (float)i0;
        float a = mother[idx * 64 + i0];
        float b = mother[idx * 64 + i0 + 1];
        v = (a + (b - a) * frac) * p.inv_sqrt_scale[idx];
    }
    kern[i] = v;
}

// ---- prep 2: Toeplitz A-matrices in MFMA A-fragment order --------------------
// chunk m of scale idx: A_m[ti][sj] = kern[16m - 16 + ti - sj]  (0 outside)
// storage: Atab[Aoff + m*512 + lane*8 + e], lane: ti=lane&31, sj=8*(lane>>5)+e
__global__ void prep_A(const float* __restrict__ kern, ushort_t* __restrict__ Atab,
                       ScaleParams p, int totalA) {
    int i = blockIdx.x * blockDim.x + threadIdx.x;
    if (i >= totalA) return;
    int idx = 0;
#pragma unroll
    for (int s = 1; s < N_SCALES; ++s)
        if (i >= p.Aoff[s]) idx = s;
    int rel = i - p.Aoff[idx];
    int m = rel >> 9;
    int r = rel & 511;
    int lane = r >> 3, e = r & 7;
    int ti = lane & 31, sj = 8 * (lane >> 5) + e;
    int kidx = 16 * m - 16 + ti - sj;
    float v = (kidx >= 0 && kidx < p.Lpad[idx]) ? kern[p.off[idx] + kidx] : 0.f;
    __hip_bfloat16 h = __float2bfloat16(v);
    Atab[i] = *reinterpret_cast<ushort_t*>(&h);
}

// ---- prep 3a: zero the left pad of the transposed signal ---------------------
__global__ void zero_pad(ushort_t* __restrict__ XT) {
    int i = blockIdx.x * blockDim.x + threadIdx.x;   // 1024 rows * 256 chunks
    int row = i >> 8, c = (i & 255) * 8;
    uint4 z = {0u, 0u, 0u, 0u};
    *reinterpret_cast<uint4*>(XT + (size_t)row * XT_STRIDE + c) = z;
}

// ---- prep 3b: transpose signal [b][s][f] fp32 -> XT[b][f][PADL+s] bf16 -------
__global__ __launch_bounds__(256) void transpose_sig(const float* __restrict__ sig,
                                                     ushort_t* __restrict__ XT) {
    __shared__ ushort_t lds[64][65];
    const int b = blockIdx.y;
    const int s0 = blockIdx.x * 64;
    const int tid = threadIdx.x;
#pragma unroll
    for (int r = 0; r < 16; ++r) {
        int i = tid + r * 256;
        int f = i & 63, sp = i >> 6;
        float v = sig[((size_t)b * S_LEN + s0 + sp) * N_FEAT + f];
        __hip_bfloat16 h = __float2bfloat16(v);
        lds[f][sp] = *reinterpret_cast<ushort_t*>(&h);
    }
    __syncthreads();
    const int f = tid >> 2, sb = (tid & 3) * 16;
    unsigned int u[8];
#pragma unroll
    for (int j = 0; j < 8; ++j)
        u[j] = (unsigned int)lds[f][sb + 2 * j] |
               ((unsigned int)lds[f][sb + 2 * j + 1] << 16);
    ushort_t* dst = XT + ((size_t)b * N_FEAT + f) * XT_STRIDE + PADL + s0 + sb;
    uint4 v0 = {u[0], u[1], u[2], u[3]};
    uint4 v1 = {u[4], u[5], u[6], u[7]};
    reinterpret_cast<uint4*>(dst)[0] = v0;
    reinterpret_cast<uint4*>(dst)[1] = v1;
}

// ---- main conv: 1 wave = 32 t x 64 f, K-chunks of 16 signal rows -------------
__global__ __launch_bounds__(256) void wavelet_mfma(
    const ushort_t* __restrict__ XT, const ushort_t* __restrict__ Atab,
    const float* __restrict__ sw, float* __restrict__ out, ScaleParams p) {
    const int idx = blockIdx.y, b = blockIdx.z;
    const int wave = threadIdx.x >> 6, lane = threadIdx.x & 63;
    const int tw0 = blockIdx.x * 128 + wave * 32;
    const int h = lane >> 5, fc = lane & 31;
    const int Mc = p.Mc[idx];

    const ushort_t* Ap = Atab + p.Aoff[idx] + lane * 8;
    const ushort_t* B0 = XT + ((size_t)(b * N_FEAT) + fc) * XT_STRIDE
                            + (PADL + tw0 + 16 + 8 * h);
    const ushort_t* B1 = B0 + (size_t)32 * XT_STRIDE;

    f32x16 acc0, acc1;
#pragma unroll
    for (int r = 0; r < 16; ++r) { acc0[r] = 0.f; acc1[r] = 0.f; }

#pragma unroll 2
    for (int m = 0; m < Mc; ++m) {
        bf16x8 a  = *reinterpret_cast<const bf16x8*>(Ap);
        bf16x8 x0 = *reinterpret_cast<const bf16x8*>(B0);
        bf16x8 x1 = *reinterpret_cast<const bf16x8*>(B1);
        acc0 = __builtin_amdgcn_mfma_f32_32x32x16_bf16(a, x0, acc0, 0, 0, 0);
        acc1 = __builtin_amdgcn_mfma_f32_32x32x16_bf16(a, x1, acc1, 0, 0, 0);
        Ap += 512; B0 -= 16; B1 -= 16;
    }

    const float w = sw[idx];
    float* ob = out + ((size_t)(b * N_SCALES + idx) * S_LEN + tw0) * N_FEAT;
#pragma unroll
    for (int r = 0; r < 16; ++r) {
        int row = (r & 3) + 8 * (r >> 2) + 4 * h;
        float v0 = acc0[r] * w, v1 = acc1[r] * w;
        ob[(size_t)row * N_FEAT + fc]      = (fabsf(v0) > THRESH) ? v0 : 0.f;
        ob[(size_t)row * N_FEAT + fc + 32] = (fabsf(v1) > THRESH) ? v1 : 0.f;
    }
}

// ---- host --------------------------------------------------------------------
extern "C" void kernel_launch(void* const* d_in, const int* in_sizes, int n_in,
                              void* d_out, int out_size, void* d_ws, size_t ws_size,
                              hipStream_t stream) {
    const float* sig    = (const float*)d_in[0];
    const float* mother = (const float*)d_in[1];
    const float* sw     = (const float*)d_in[2];
    float* out = (float*)d_out;

    float*    kern = (float*)d_ws;                              // 5168 f32
    ushort_t* Atab = (ushort_t*)((char*)d_ws + 32768);          // ~347 KB
    ushort_t* XT   = (ushort_t*)((char*)d_ws + 524288);         // 12.58 MB

    ScaleParams p;
    int off = 0, aoff = 0;
    for (int i = 0; i < N_SCALES; ++i) {
        double scale = pow(10.0, (double)i * log10(32.0) / 7.0);
        double v = 64.0 * scale;
        double r = floor(v + 0.5);
        int L = (fabs(v - r) < 1e-6) ? (int)r : (int)v;
        p.L[i] = L;
        p.Lpad[i] = (L + 15) & ~15;
        p.off[i] = off;           off += p.Lpad[i];
        p.Mc[i] = (L + 46) >> 4;  // ceil((L+31)/16)
        p.Aoff[i] = aoff;         aoff += p.Mc[i] * 512;
        p.inv_sqrt_scale[i] = (float)(1.0 / sqrt(scale));
        p.step[i] = (float)(63.0 / (double)(L - 1));
    }
    const int totalK = off;      // 5168
    const int totalA = aoff;     // 339*512

    build_kernels<<<dim3((totalK + 255) / 256), dim3(256), 0, stream>>>(
        mother, kern, p, totalK);
    prep_A<<<dim3((totalA + 255) / 256), dim3(256), 0, stream>>>(
        kern, Atab, p, totalA);
    zero_pad<<<dim3(1024), dim3(256), 0, stream>>>(XT);
    transpose_sig<<<dim3(S_LEN / 64, N_BATCH), dim3(256), 0, stream>>>(sig, XT);

    wavelet_mfma<<<dim3(S_LEN / 128, N_SCALES, N_BATCH), dim3(256), 0, stream>>>(
        XT, Atab, sw, out, p);
}

// Round 3
// 208.028 us; speedup vs baseline: 3.9080x; 1.3049x over previous
//
#include <hip/hip_runtime.h>
#include <hip/hip_bf16.h>
#include <math.h>

#define S_LEN 4096
#define N_FEAT 64
#define N_BATCH 16
#define N_SCALES 8
#define THRESH 1e-4f
#define PADL 2048
#define XT_STRIDE (PADL + S_LEN)   // 6144 bf16 elems per (b,f) row

typedef unsigned short ushort_t;
typedef __attribute__((ext_vector_type(8))) short bf16x8;
typedef __attribute__((ext_vector_type(16))) float f32x16;

struct ScaleParams {
    int L[N_SCALES], Lpad[N_SCALES], off[N_SCALES];
    int Mc[N_SCALES], Aoff[N_SCALES];          // Aoff in ushort elems
    float inv_sqrt_scale[N_SCALES], step[N_SCALES];
};

// ---- prep 1: dilated, interpolated, normalized kernels (fp32, Lpad-padded) --
__global__ void build_kernels(const float* __restrict__ mother,
                              float* __restrict__ kern,
                              ScaleParams p, int total) {
    int i = blockIdx.x * blockDim.x + threadIdx.x;
    if (i >= total) return;
    int idx = 0;
#pragma unroll
    for (int s = 1; s < N_SCALES; ++s)
        if (i >= p.off[s]) idx = s;
    int l = i - p.off[idx];
    float v = 0.f;
    if (l < p.L[idx]) {
        float xq = fminf(l * p.step[idx], 63.0f);
        int i0 = (int)xq; if (i0 > 62) i0 = 62;
        float frac = xq - (float)i0;
        float a = mother[idx * 64 + i0];
        float b = mother[idx * 64 + i0 + 1];
        v = (a + (b - a) * frac) * p.inv_sqrt_scale[idx];
    }
    kern[i] = v;
}

// ---- prep 2: Toeplitz A-matrices in MFMA A-fragment order --------------------
// chunk m: A_m[ti][sj] = kern[16m - 16 + ti - sj] (0 outside); Mc+3 chunks/scale
// (chunks >= Mc read only the zero tail of kern -> all-zero pad chunks)
__global__ void prep_A(const float* __restrict__ kern, ushort_t* __restrict__ Atab,
                       ScaleParams p, int totalA) {
    int i = blockIdx.x * blockDim.x + threadIdx.x;
    if (i >= totalA) return;
    int idx = 0;
#pragma unroll
    for (int s = 1; s < N_SCALES; ++s)
        if (i >= p.Aoff[s]) idx = s;
    int rel = i - p.Aoff[idx];
    int m = rel >> 9;
    int r = rel & 511;
    int lane = r >> 3, e = r & 7;
    int ti = lane & 31, sj = 8 * (lane >> 5) + e;
    int kidx = 16 * m - 16 + ti - sj;
    float v = (kidx >= 0 && kidx < p.Lpad[idx]) ? kern[p.off[idx] + kidx] : 0.f;
    __hip_bfloat16 hh = __float2bfloat16(v);
    Atab[i] = *reinterpret_cast<ushort_t*>(&hh);
}

// ---- prep 3a: zero the left pad of the transposed signal ---------------------
__global__ void zero_pad(ushort_t* __restrict__ XT) {
    int i = blockIdx.x * blockDim.x + threadIdx.x;   // 1024 rows * 256 chunks
    int row = i >> 8, c = (i & 255) * 8;
    uint4 z = {0u, 0u, 0u, 0u};
    *reinterpret_cast<uint4*>(XT + (size_t)row * XT_STRIDE + c) = z;
}

// ---- prep 3b: transpose signal [b][s][f] fp32 -> XT[b][f][PADL+s] bf16 -------
__global__ __launch_bounds__(256) void transpose_sig(const float* __restrict__ sig,
                                                     ushort_t* __restrict__ XT) {
    __shared__ ushort_t lds[64][65];
    const int b = blockIdx.y;
    const int s0 = blockIdx.x * 64;
    const int tid = threadIdx.x;
#pragma unroll
    for (int r = 0; r < 16; ++r) {
        int i = tid + r * 256;
        int f = i & 63, sp = i >> 6;
        float v = sig[((size_t)b * S_LEN + s0 + sp) * N_FEAT + f];
        __hip_bfloat16 hh = __float2bfloat16(v);
        lds[f][sp] = *reinterpret_cast<ushort_t*>(&hh);
    }
    __syncthreads();
    const int f = tid >> 2, sb = (tid & 3) * 16;
    unsigned int u[8];
#pragma unroll
    for (int j = 0; j < 8; ++j)
        u[j] = (unsigned int)lds[f][sb + 2 * j] |
               ((unsigned int)lds[f][sb + 2 * j + 1] << 16);
    ushort_t* dst = XT + ((size_t)b * N_FEAT + f) * XT_STRIDE + PADL + s0 + sb;
    uint4 v0 = {u[0], u[1], u[2], u[3]};
    uint4 v1 = {u[4], u[5], u[6], u[7]};
    reinterpret_cast<uint4*>(dst)[0] = v0;
    reinterpret_cast<uint4*>(dst)[1] = v1;
}

// ---- main conv: 1 wave = 64 t x 64 f (2 Toeplitz subtiles share B stream) ----
__global__ __launch_bounds__(256) void wavelet_mfma(
    const ushort_t* __restrict__ XT, const ushort_t* __restrict__ Atab,
    const float* __restrict__ sw, float* __restrict__ out, ScaleParams p) {
    const int idx = blockIdx.y, b = blockIdx.z;
    const int wave = threadIdx.x >> 6, lane = threadIdx.x & 63;
    const int tw0 = blockIdx.x * 256 + wave * 64;
    const int h = lane >> 5, fc = lane & 31;
    const int Mc = p.Mc[idx];

    const ushort_t* Ab = Atab + p.Aoff[idx] + lane * 8;       // chunk c: +c*512
    const ushort_t* Bb = XT + ((size_t)(b * N_FEAT) + fc) * XT_STRIDE
                            + (PADL + tw0 + 16 + 8 * h);      // B_m: -16*m
    const size_t fhi = (size_t)32 * XT_STRIDE;

    f32x16 a00, a01, a10, a11;
#pragma unroll
    for (int r = 0; r < 16; ++r) { a00[r] = 0.f; a01[r] = 0.f; a10[r] = 0.f; a11[r] = 0.f; }

    // peel mm = -2,-1: only subtile1 (chunk mm+2) active
#pragma unroll
    for (int mm = -2; mm < 0; ++mm) {
        bf16x8 A1 = *reinterpret_cast<const bf16x8*>(Ab + (mm + 2) * 512);
        bf16x8 X0 = *reinterpret_cast<const bf16x8*>(Bb - 16 * mm);
        bf16x8 X1 = *reinterpret_cast<const bf16x8*>(Bb - 16 * mm + fhi);
        a10 = __builtin_amdgcn_mfma_f32_32x32x16_bf16(A1, X0, a10, 0, 0, 0);
        a11 = __builtin_amdgcn_mfma_f32_32x32x16_bf16(A1, X1, a11, 0, 0, 0);
    }

    // preload mm = 0
    bf16x8 A0 = *reinterpret_cast<const bf16x8*>(Ab);
    bf16x8 A1 = *reinterpret_cast<const bf16x8*>(Ab + 2 * 512);
    bf16x8 X0 = *reinterpret_cast<const bf16x8*>(Bb);
    bf16x8 X1 = *reinterpret_cast<const bf16x8*>(Bb + fhi);

#pragma unroll 2
    for (int mm = 0; mm < Mc; ++mm) {
        const int mn = mm + 1;
        const int mnc = (mn < Mc) ? mn : (Mc - 1);
        bf16x8 nA0 = *reinterpret_cast<const bf16x8*>(Ab + mn * 512);       // <= Mc (padded)
        bf16x8 nA1 = *reinterpret_cast<const bf16x8*>(Ab + (mn + 2) * 512); // <= Mc+2 (padded)
        bf16x8 nX0 = *reinterpret_cast<const bf16x8*>(Bb - 16 * mnc);
        bf16x8 nX1 = *reinterpret_cast<const bf16x8*>(Bb - 16 * mnc + fhi);
        a00 = __builtin_amdgcn_mfma_f32_32x32x16_bf16(A0, X0, a00, 0, 0, 0);
        a01 = __builtin_amdgcn_mfma_f32_32x32x16_bf16(A0, X1, a01, 0, 0, 0);
        a10 = __builtin_amdgcn_mfma_f32_32x32x16_bf16(A1, X0, a10, 0, 0, 0);
        a11 = __builtin_amdgcn_mfma_f32_32x32x16_bf16(A1, X1, a11, 0, 0, 0);
        A0 = nA0; A1 = nA1; X0 = nX0; X1 = nX1;
    }

    const float w = sw[idx];
    float* ob = out + ((size_t)(b * N_SCALES + idx) * S_LEN + tw0) * N_FEAT + fc;
#pragma unroll
    for (int r = 0; r < 16; ++r) {
        const int row = (r & 3) + 8 * (r >> 2) + 4 * h;
        float v;
        v = a00[r] * w; ob[(size_t)row * N_FEAT]             = (fabsf(v) > THRESH) ? v : 0.f;
        v = a01[r] * w; ob[(size_t)row * N_FEAT + 32]        = (fabsf(v) > THRESH) ? v : 0.f;
        v = a10[r] * w; ob[(size_t)(row + 32) * N_FEAT]      = (fabsf(v) > THRESH) ? v : 0.f;
        v = a11[r] * w; ob[(size_t)(row + 32) * N_FEAT + 32] = (fabsf(v) > THRESH) ? v : 0.f;
    }
}

// ---- host --------------------------------------------------------------------
extern "C" void kernel_launch(void* const* d_in, const int* in_sizes, int n_in,
                              void* d_out, int out_size, void* d_ws, size_t ws_size,
                              hipStream_t stream) {
    const float* sig    = (const float*)d_in[0];
    const float* mother = (const float*)d_in[1];
    const float* sw     = (const float*)d_in[2];
    float* out = (float*)d_out;

    float*    kern = (float*)d_ws;                              // 5168 f32
    ushort_t* Atab = (ushort_t*)((char*)d_ws + 32768);          // ~372 KB
    ushort_t* XT   = (ushort_t*)((char*)d_ws + 524288);         // 12.58 MB

    ScaleParams p;
    int off = 0, aoff = 0;
    for (int i = 0; i < N_SCALES; ++i) {
        double scale = pow(10.0, (double)i * log10(32.0) / 7.0);
        double v = 64.0 * scale;
        double r = floor(v + 0.5);
        int L = (fabs(v - r) < 1e-6) ? (int)r : (int)v;
        p.L[i] = L;
        p.Lpad[i] = (L + 15) & ~15;
        p.off[i] = off;           off += p.Lpad[i];
        p.Mc[i] = (L + 46) >> 4;  // ceil((L+31)/16)
        p.Aoff[i] = aoff;         aoff += (p.Mc[i] + 3) * 512;  // +3 zero pad chunks
        p.inv_sqrt_scale[i] = (float)(1.0 / sqrt(scale));
        p.step[i] = (float)(63.0 / (double)(L - 1));
    }
    const int totalK = off;      // 5168
    const int totalA = aoff;     // 363*512

    build_kernels<<<dim3((totalK + 255) / 256), dim3(256), 0, stream>>>(
        mother, kern, p, totalK);
    prep_A<<<dim3((totalA + 255) / 256), dim3(256), 0, stream>>>(
        kern, Atab, p, totalA);
    zero_pad<<<dim3(1024), dim3(256), 0, stream>>>(XT);
    transpose_sig<<<dim3(S_LEN / 64, N_BATCH), dim3(256), 0, stream>>>(sig, XT);

    wavelet_mfma<<<dim3(S_LEN / 256, N_SCALES, N_BATCH), dim3(256), 0, stream>>>(
        XT, Atab, sw, out, p);
}

// Round 4
// 87.262 us; speedup vs baseline: 9.3165x; 2.3839x over previous
//
#include <hip/hip_runtime.h>
#include <hip/hip_bf16.h>
#include <math.h>

#define S_LEN 4096
#define N_FEAT 64
#define N_BATCH 16
#define N_SCALES 8
#define THRESH 1e-4f
#define PADL 2048
#define NCHUNK ((PADL + S_LEN) / 16)    // 384 chunks of 16 s-values
#define CHUNK_ELEMS 1024                // [h:2][f:64][e:8] bf16

typedef unsigned short ushort_t;
typedef __attribute__((ext_vector_type(8))) short bf16x8;
typedef __attribute__((ext_vector_type(16))) float f32x16;

struct ScaleParams {
    int L[N_SCALES], Lpad[N_SCALES], off[N_SCALES];
    int Mc[N_SCALES], Aoff[N_SCALES];          // Aoff in ushort elems
    float inv_sqrt_scale[N_SCALES], step[N_SCALES];
};

// ---- prep 1: dilated, interpolated, normalized kernels (fp32, Lpad-padded) --
__global__ void build_kernels(const float* __restrict__ mother,
                              float* __restrict__ kern,
                              ScaleParams p, int total) {
    int i = blockIdx.x * blockDim.x + threadIdx.x;
    if (i >= total) return;
    int idx = 0;
#pragma unroll
    for (int s = 1; s < N_SCALES; ++s)
        if (i >= p.off[s]) idx = s;
    int l = i - p.off[idx];
    float v = 0.f;
    if (l < p.L[idx]) {
        float xq = fminf(l * p.step[idx], 63.0f);
        int i0 = (int)xq; if (i0 > 62) i0 = 62;
        float frac = xq - (float)i0;
        float a = mother[idx * 64 + i0];
        float b = mother[idx * 64 + i0 + 1];
        v = (a + (b - a) * frac) * p.inv_sqrt_scale[idx];
    }
    kern[i] = v;
}

// ---- prep 2: Toeplitz A-matrices in MFMA A-fragment order --------------------
// chunk m: A_m[ti][sj] = kern[16m - 16 + ti - sj] (0 outside); Mc+3 chunks/scale
__global__ void prep_A(const float* __restrict__ kern, ushort_t* __restrict__ Atab,
                       ScaleParams p, int totalA) {
    int i = blockIdx.x * blockDim.x + threadIdx.x;
    if (i >= totalA) return;
    int idx = 0;
#pragma unroll
    for (int s = 1; s < N_SCALES; ++s)
        if (i >= p.Aoff[s]) idx = s;
    int rel = i - p.Aoff[idx];
    int m = rel >> 9;
    int r = rel & 511;
    int lane = r >> 3, e = r & 7;
    int ti = lane & 31, sj = 8 * (lane >> 5) + e;
    int kidx = 16 * m - 16 + ti - sj;
    float v = (kidx >= 0 && kidx < p.Lpad[idx]) ? kern[p.off[idx] + kidx] : 0.f;
    __hip_bfloat16 hh = __float2bfloat16(v);
    Atab[i] = *reinterpret_cast<ushort_t*>(&hh);
}

// ---- prep 3: signal [b][s][f] fp32 -> fragment-major XTc[b][G][f][e] bf16 ----
// G = global 8-s group (chunk c = G>>1, half h = G&1); s_padded = 8G + e.
// Reads: per e, 64 lanes read sig[s][0..63] = 256 B coalesced.
// Writes: lane l stores 16 B at G*512 + l*8 -> 1 KB contiguous per wave.
__global__ __launch_bounds__(256) void transpose_sig(const float* __restrict__ sig,
                                                     ushort_t* __restrict__ XTc) {
    const int b = blockIdx.y;
    const int G = blockIdx.x * 4 + (threadIdx.x >> 6);
    const int l = threadIdx.x & 63;
    unsigned int u[4];
    if (G < PADL / 8) {
        u[0] = u[1] = u[2] = u[3] = 0u;
    } else {
        const float* sp = sig + ((size_t)b * S_LEN + ((size_t)G * 8 - PADL)) * N_FEAT + l;
#pragma unroll
        for (int j = 0; j < 4; ++j) {
            float v0 = sp[(size_t)(2 * j) * N_FEAT];
            float v1 = sp[(size_t)(2 * j + 1) * N_FEAT];
            __hip_bfloat16 h0 = __float2bfloat16(v0);
            __hip_bfloat16 h1 = __float2bfloat16(v1);
            u[j] = (unsigned int)*reinterpret_cast<ushort_t*>(&h0) |
                   ((unsigned int)*reinterpret_cast<ushort_t*>(&h1) << 16);
        }
    }
    uint4 vv = {u[0], u[1], u[2], u[3]};
    *reinterpret_cast<uint4*>(XTc + (size_t)b * (NCHUNK * CHUNK_ELEMS)
                              + (size_t)G * 512 + l * 8) = vv;
}

// ---- main conv: 1 wave = 64 t x 64 f; all operand loads 1 KB coalesced -------
__global__ __launch_bounds__(256) void wavelet_mfma(
    const ushort_t* __restrict__ XTc, const ushort_t* __restrict__ Atab,
    const float* __restrict__ sw, float* __restrict__ out, ScaleParams p) {
    const int idx = 7 - blockIdx.z;            // longest scales dispatched first
    const int b = blockIdx.y;
    const int wave = threadIdx.x >> 6, lane = threadIdx.x & 63;
    const int tw0 = blockIdx.x * 256 + wave * 64;
    const int h = lane >> 5, fc = lane & 31;
    const int Mc = p.Mc[idx];

    const ushort_t* Ab = Atab + p.Aoff[idx] + lane * 8;        // chunk c: +c*512
    const int c0 = (PADL + tw0) / 16 + 1;
    const ushort_t* Bp = XTc + (size_t)b * (NCHUNK * CHUNK_ELEMS)
                       + (size_t)(c0 * 2 + h) * 512 + fc * 8;  // chunk m: -m*1024

    f32x16 a00, a01, a10, a11;
#pragma unroll
    for (int r = 0; r < 16; ++r) { a00[r] = 0.f; a01[r] = 0.f; a10[r] = 0.f; a11[r] = 0.f; }

    // peel mm = -2,-1: only subtile1 (A chunk mm+2) active
#pragma unroll
    for (int mm = -2; mm < 0; ++mm) {
        const ushort_t* q = Bp + (size_t)(-mm) * 1024;
        bf16x8 A1p = *reinterpret_cast<const bf16x8*>(Ab + (mm + 2) * 512);
        bf16x8 X0p = *reinterpret_cast<const bf16x8*>(q);
        bf16x8 X1p = *reinterpret_cast<const bf16x8*>(q + 256);
        a10 = __builtin_amdgcn_mfma_f32_32x32x16_bf16(A1p, X0p, a10, 0, 0, 0);
        a11 = __builtin_amdgcn_mfma_f32_32x32x16_bf16(A1p, X1p, a11, 0, 0, 0);
    }

    // preload mm = 0
    bf16x8 A0 = *reinterpret_cast<const bf16x8*>(Ab);
    bf16x8 A1 = *reinterpret_cast<const bf16x8*>(Ab + 1024);
    bf16x8 X0 = *reinterpret_cast<const bf16x8*>(Bp);
    bf16x8 X1 = *reinterpret_cast<const bf16x8*>(Bp + 256);

#pragma unroll 2
    for (int mm = 0; mm < Mc; ++mm) {
        const int mn = mm + 1;
        const int mnc = (mn < Mc) ? mn : (Mc - 1);
        const ushort_t* qa = Ab + (size_t)mn * 512;
        const ushort_t* qb = Bp - (size_t)mnc * 1024;
        bf16x8 nA0 = *reinterpret_cast<const bf16x8*>(qa);         // <= Mc (padded)
        bf16x8 nA1 = *reinterpret_cast<const bf16x8*>(qa + 1024);  // <= Mc+2 (padded)
        bf16x8 nX0 = *reinterpret_cast<const bf16x8*>(qb);
        bf16x8 nX1 = *reinterpret_cast<const bf16x8*>(qb + 256);
        a00 = __builtin_amdgcn_mfma_f32_32x32x16_bf16(A0, X0, a00, 0, 0, 0);
        a01 = __builtin_amdgcn_mfma_f32_32x32x16_bf16(A0, X1, a01, 0, 0, 0);
        a10 = __builtin_amdgcn_mfma_f32_32x32x16_bf16(A1, X0, a10, 0, 0, 0);
        a11 = __builtin_amdgcn_mfma_f32_32x32x16_bf16(A1, X1, a11, 0, 0, 0);
        A0 = nA0; A1 = nA1; X0 = nX0; X1 = nX1;
    }

    const float w = sw[idx];
    float* ob = out + ((size_t)(b * N_SCALES + idx) * S_LEN + tw0) * N_FEAT + fc;
#pragma unroll
    for (int r = 0; r < 16; ++r) {
        const int row = (r & 3) + 8 * (r >> 2) + 4 * h;
        float v;
        v = a00[r] * w; v = (fabsf(v) > THRESH) ? v : 0.f;
        __builtin_nontemporal_store(v, &ob[(size_t)row * N_FEAT]);
        v = a01[r] * w; v = (fabsf(v) > THRESH) ? v : 0.f;
        __builtin_nontemporal_store(v, &ob[(size_t)row * N_FEAT + 32]);
        v = a10[r] * w; v = (fabsf(v) > THRESH) ? v : 0.f;
        __builtin_nontemporal_store(v, &ob[(size_t)(row + 32) * N_FEAT]);
        v = a11[r] * w; v = (fabsf(v) > THRESH) ? v : 0.f;
        __builtin_nontemporal_store(v, &ob[(size_t)(row + 32) * N_FEAT + 32]);
    }
}

// ---- host --------------------------------------------------------------------
extern "C" void kernel_launch(void* const* d_in, const int* in_sizes, int n_in,
                              void* d_out, int out_size, void* d_ws, size_t ws_size,
                              hipStream_t stream) {
    const float* sig    = (const float*)d_in[0];
    const float* mother = (const float*)d_in[1];
    const float* sw     = (const float*)d_in[2];
    float* out = (float*)d_out;

    float*    kern = (float*)d_ws;                              // 5168 f32
    ushort_t* Atab = (ushort_t*)((char*)d_ws + 32768);          // ~372 KB
    ushort_t* XTc  = (ushort_t*)((char*)d_ws + 524288);         // 12.58 MB

    ScaleParams p;
    int off = 0, aoff = 0;
    for (int i = 0; i < N_SCALES; ++i) {
        double scale = pow(10.0, (double)i * log10(32.0) / 7.0);
        double v = 64.0 * scale;
        double r = floor(v + 0.5);
        int L = (fabs(v - r) < 1e-6) ? (int)r : (int)v;
        p.L[i] = L;
        p.Lpad[i] = (L + 15) & ~15;
        p.off[i] = off;           off += p.Lpad[i];
        p.Mc[i] = (L + 46) >> 4;  // ceil((L+31)/16)
        p.Aoff[i] = aoff;         aoff += (p.Mc[i] + 3) * 512;  // +3 zero pad chunks
        p.inv_sqrt_scale[i] = (float)(1.0 / sqrt(scale));
        p.step[i] = (float)(63.0 / (double)(L - 1));
    }
    const int totalK = off;      // 5168
    const int totalA = aoff;     // 363*512

    build_kernels<<<dim3((totalK + 255) / 256), dim3(256), 0, stream>>>(
        mother, kern, p, totalK);
    prep_A<<<dim3((totalA + 255) / 256), dim3(256), 0, stream>>>(
        kern, Atab, p, totalA);
    transpose_sig<<<dim3((PADL + S_LEN) / 32, N_BATCH), dim3(256), 0, stream>>>(
        sig, XTc);

    wavelet_mfma<<<dim3(S_LEN / 256, N_BATCH, N_SCALES), dim3(256), 0, stream>>>(
        XTc, Atab, sw, out, p);
}